// Round 1
// baseline (444.776 us; speedup 1.0000x reference)
//
#include <hip/hip_runtime.h>
#include <math.h>

#define A_N   8732
#define C_N   81
#define B_N   32
#define NCLS  80
#define TOPK  100
#define CAND  1024
#define NTHR  256

// Monotone map: float bits -> unsigned, preserving total order of floats.
__device__ __forceinline__ unsigned mapf(float x) {
    unsigned b = __float_as_uint(x);
    return b ^ ((b & 0x80000000u) ? 0xFFFFFFFFu : 0x80000000u);
}

__global__ __launch_bounds__(NTHR) void ssd_nms_kernel(
    const float* __restrict__ logits,   // (B, A, C)
    const float* __restrict__ boxreg,   // (B, A, 4)
    const float* __restrict__ priors,   // (A, 4)
    float* __restrict__ out)            // (B, 80, 100, 5)
{
    const int task = blockIdx.x;
    const int b = task / NCLS;
    const int c = task % NCLS;            // fg class -> logits channel c+1
    const int tid = threadIdx.x;

    __shared__ unsigned uval[A_N];
    __shared__ unsigned hist[256];
    __shared__ unsigned long long cand[CAND];
    __shared__ int scal[4];               // [0]=gather count, [1]=k1, [2]=n_above, [3]=cutoff
    __shared__ double sb0[TOPK], sb1[TOPK], sb2[TOPK], sb3[TOPK];
    __shared__ double sarea[TOPK], sscore[TOPK];
    __shared__ int skeep[TOPK], svalid[TOPK];

    const float* lg = logits + ((size_t)b * A_N * C_N) + (c + 1);

    // ---- Phase 1: per-anchor monotone keys; validity = sigmoid_f64(x) > 0.3
    for (int a = tid; a < A_N; a += NTHR) {
        float x = lg[(size_t)a * C_N];
        double s = 1.0 / (1.0 + exp(-(double)x));
        uval[a] = (s > 0.3) ? mapf(x) : 0u;   // 0 marks invalid (valid keys are always > 0)
    }
    for (int k = tid; k < 256; k += NTHR) hist[k] = 0;
    __syncthreads();

    // ---- Phase 2: level-1 histogram on top byte of key
    for (int a = tid; a < A_N; a += NTHR) {
        unsigned u = uval[a];
        if (u) atomicAdd(&hist[u >> 24], 1u);
    }
    __syncthreads();
    if (tid == 0) {
        unsigned run = 0; int k1 = -1; unsigned n_above = 0;
        for (int k = 255; k >= 0; --k) {
            unsigned rn = run + hist[k];
            if (rn >= TOPK) { k1 = k; n_above = run; break; }
            run = rn;
        }
        scal[0] = 0;
        scal[1] = k1;
        scal[2] = (int)n_above;
        scal[3] = 1;                       // default cutoff: take every valid key
    }
    __syncthreads();
    const int k1 = scal[1];

    // ---- Phase 3: level-2 histogram inside the crossing bucket (uniform branch)
    for (int k = tid; k < 256; k += NTHR) hist[k] = 0;
    __syncthreads();
    if (k1 >= 0) {
        for (int a = tid; a < A_N; a += NTHR) {
            unsigned u = uval[a];
            if (u && (int)(u >> 24) == k1) atomicAdd(&hist[(u >> 16) & 0xFFu], 1u);
        }
    }
    __syncthreads();
    if (tid == 0 && k1 >= 0) {
        unsigned run = (unsigned)scal[2]; int k2 = 0;
        for (int k = 255; k >= 0; --k) {
            run += hist[k];
            if (run >= TOPK) { k2 = k; break; }
        }
        scal[3] = (int)(((unsigned)k1 << 24) | ((unsigned)k2 << 16));
    }
    __syncthreads();
    const unsigned cutoff = (unsigned)scal[3];

    // ---- Phase 4: gather candidates >= cutoff; key = (u<<32) | ~idx
    //      (descending sort => score desc, then index asc on ties)
    for (int a = tid; a < A_N; a += NTHR) {
        unsigned u = uval[a];
        if (u >= cutoff && u != 0u) {
            int pos = atomicAdd(&scal[0], 1);
            if (pos < CAND)
                cand[pos] = ((unsigned long long)u << 32) | (unsigned)(~(unsigned)a);
        }
    }
    __syncthreads();
    const int M = min(scal[0], CAND);
    for (int i = tid; i < CAND; i += NTHR) if (i >= M) cand[i] = 0ull;
    __syncthreads();

    // ---- Phase 5: bitonic sort CAND keys, descending
    for (int k = 2; k <= CAND; k <<= 1) {
        for (int j = k >> 1; j > 0; j >>= 1) {
            for (int t = tid; t < CAND; t += NTHR) {
                int ixj = t ^ j;
                if (ixj > t) {
                    unsigned long long x0 = cand[t], x1 = cand[ixj];
                    bool descSeg = ((t & k) == 0);
                    bool sw = descSeg ? (x0 < x1) : (x0 > x1);
                    if (sw) { cand[t] = x1; cand[ixj] = x0; }
                }
            }
            __syncthreads();
        }
    }

    // ---- Phase 6: decode top-100 boxes in f64 (mirrors numpy op order)
    if (tid < TOPK) {
        unsigned long long key = cand[tid];
        int valid = (key != 0ull);
        double b0 = 0, b1 = 0, b2 = 0, b3 = 0, area = 0, sc = 0;
        if (valid) {
            int a = (int)(~(unsigned)key);
            float x = lg[(size_t)a * C_N];
            sc = 1.0 / (1.0 + exp(-(double)x));
            const float* r4 = boxreg + ((size_t)b * A_N + a) * 4;
            const float* p4 = priors + (size_t)a * 4;
            double ty = (double)r4[0] / 10.0;
            double tx = (double)r4[1] / 10.0;
            double th = (double)r4[2] / 5.0;
            double tw = (double)r4[3] / 5.0;
            double py = (double)p4[0], px = (double)p4[1];
            double ph = (double)p4[2], pw = (double)p4[3];
            double cy = ty * ph + py;
            double cx = tx * pw + px;
            double hh = exp(th) * ph;
            double ww = exp(tw) * pw;
            b0 = cy - hh / 2.0; b1 = cx - ww / 2.0;
            b2 = cy + hh / 2.0; b3 = cx + ww / 2.0;
            double e0 = b2 - b0; if (e0 < 0.0) e0 = 0.0;
            double e1 = b3 - b1; if (e1 < 0.0) e1 = 0.0;
            area = e0 * e1;
        }
        sb0[tid] = b0; sb1[tid] = b1; sb2[tid] = b2; sb3[tid] = b3;
        sarea[tid] = area; sscore[tid] = sc;
        skeep[tid] = 1; svalid[tid] = valid;
    }
    __syncthreads();

    // ---- Phase 7: greedy NMS, f64 IoU, exact reference op order
    const int j = tid;
    double bj0 = 0, bj1 = 0, bj2 = 0, bj3 = 0, aj = 0;
    if (j < TOPK) { bj0 = sb0[j]; bj1 = sb1[j]; bj2 = sb2[j]; bj3 = sb3[j]; aj = sarea[j]; }
    for (int i = 0; i < TOPK - 1; ++i) {
        __syncthreads();   // make suppressions from iteration i-1 visible
        if (j < TOPK && j > i && skeep[i] && svalid[i] && skeep[j]) {
            double tl0 = fmax(sb0[i], bj0);
            double tl1 = fmax(sb1[i], bj1);
            double br0 = fmin(sb2[i], bj2);
            double br1 = fmin(sb3[i], bj3);
            double wh0 = br0 - tl0; if (wh0 < 0.0) wh0 = 0.0;
            double wh1 = br1 - tl1; if (wh1 < 0.0) wh1 = 0.0;
            double inter = wh0 * wh1;
            double iou = inter / (((sarea[i] + aj) - inter) + 1e-9);
            if (iou > 0.6) skeep[j] = 0;
        }
    }
    __syncthreads();

    // ---- Phase 8: write 5 floats per slot
    if (j < TOPK) {
        size_t base = ((size_t)task * TOPK + j) * 5;
        bool kp = (skeep[j] != 0) && (svalid[j] != 0);
        out[base + 0] = kp ? (float)bj0 : 0.0f;
        out[base + 1] = kp ? (float)bj1 : 0.0f;
        out[base + 2] = kp ? (float)bj2 : 0.0f;
        out[base + 3] = kp ? (float)bj3 : 0.0f;
        out[base + 4] = kp ? (float)sscore[j] : 0.0f;
    }
}

extern "C" void kernel_launch(void* const* d_in, const int* in_sizes, int n_in,
                              void* d_out, int out_size, void* d_ws, size_t ws_size,
                              hipStream_t stream) {
    const float* logits = (const float*)d_in[0];   // class_logits (B,A,C) f32
    const float* boxreg = (const float*)d_in[1];   // box_regression (B,A,4) f32
    const float* priors = (const float*)d_in[2];   // priors (A,4) f32
    float* out = (float*)d_out;

    hipLaunchKernelGGL(ssd_nms_kernel, dim3(B_N * NCLS), dim3(NTHR), 0, stream,
                       logits, boxreg, priors, out);
}

// Round 2
// 330.225 us; speedup vs baseline: 1.3469x; 1.3469x over previous
//
#include <hip/hip_runtime.h>
#include <math.h>

#define A_N   8732
#define C_N   81
#define B_N   32
#define NCLS  80
#define TOPK  100
#define CAND  256
#define NTHR  256
#define TA    128

// ln(3/7) in f64: sigmoid_f64(x) > 0.3  <=>  x > THR_LOGIT
#define THR_LOGIT (-0.8472978603872034)

// Monotone map: float bits -> unsigned, preserving total order. 0 = invalid sentinel.
__device__ __forceinline__ unsigned mapf(float x) {
    unsigned b = __float_as_uint(x);
    return b ^ ((b & 0x80000000u) ? 0xFFFFFFFFu : 0x80000000u);
}
__device__ __forceinline__ float unmapf(unsigned u) {
    unsigned b = (u & 0x80000000u) ? (u ^ 0x80000000u) : ~u;
    return __uint_as_float(b);
}

// ---- Kernel T: coalesced read of logits, write keys transposed to (B, 80, A) ----
__global__ __launch_bounds__(NTHR) void key_transpose_kernel(
    const float* __restrict__ logits,    // (B, A, 81)
    unsigned* __restrict__ keys)         // (B, 80, A)
{
    __shared__ unsigned tile[NCLS][TA + 1];   // 80 x 129 words = 41.3 KB
    const int NT = (A_N + TA - 1) / TA;       // 69
    const int b  = blockIdx.x / NT;
    const int t0 = blockIdx.x % NT;
    const int a0 = t0 * TA;
    const int an = min(TA, A_N - a0);
    const int tid = threadIdx.x;

    const float* src = logits + ((size_t)b * A_N + a0) * C_N;
    const int total = an * C_N;
    for (int i = tid; i < total; i += NTHR) {
        int r = i / C_N;
        int ch = i - r * C_N;
        float x = src[i];
        if (ch > 0) {
            unsigned u = ((double)x > THR_LOGIT) ? mapf(x) : 0u;
            tile[ch - 1][r] = u;
        }
    }
    __syncthreads();
    for (int i = tid; i < NCLS * TA; i += NTHR) {
        int row = i / TA;
        int col = i - row * TA;
        if (col < an)
            keys[((size_t)b * NCLS + row) * A_N + a0 + col] = tile[row][col];
    }
}

// ---- Kernel M: per-(b,c) top-100 select + decode + NMS ----
template<bool USE_WS>
__global__ __launch_bounds__(NTHR) void ssd_nms_kernel(
    const float* __restrict__ logits,
    const unsigned* __restrict__ keys,
    const float* __restrict__ boxreg,
    const float* __restrict__ priors,
    float* __restrict__ out)
{
    const int task = blockIdx.x;
    const int b = task / NCLS;
    const int c = task % NCLS;
    const int tid = threadIdx.x;

    __shared__ __align__(16) unsigned uval[A_N];
    __shared__ unsigned hist[256];
    __shared__ unsigned long long cand[CAND];
    __shared__ unsigned long long ssel[TOPK];
    __shared__ double sb0[TOPK], sb1[TOPK], sb2[TOPK], sb3[TOPK];
    __shared__ double sarea[TOPK], sscore[TOPK];
    __shared__ int svalid[TOPK];
    __shared__ unsigned long long supmask[TOPK][2];
    __shared__ unsigned long long keepw[2];
    __shared__ int scal[8];

    // ---- init + stage keys + level-1 histogram (top byte)
    hist[tid] = 0;
    cand[tid] = 0;
    if (tid < TOPK) ssel[tid] = 0;
    if (tid == 0) scal[0] = 0;
    __syncthreads();

    if (USE_WS) {
        const uint4* src = (const uint4*)(keys + ((size_t)b * NCLS + c) * A_N);
        for (int i = tid; i < A_N / 4; i += NTHR) {
            uint4 v = src[i];
            ((uint4*)uval)[i] = v;
            if (v.x) atomicAdd(&hist[v.x >> 24], 1u);
            if (v.y) atomicAdd(&hist[v.y >> 24], 1u);
            if (v.z) atomicAdd(&hist[v.z >> 24], 1u);
            if (v.w) atomicAdd(&hist[v.w >> 24], 1u);
        }
    } else {
        const float* lg = logits + ((size_t)b * A_N * C_N) + (c + 1);
        for (int a = tid; a < A_N; a += NTHR) {
            float x = lg[(size_t)a * C_N];
            unsigned u = ((double)x > THR_LOGIT) ? mapf(x) : 0u;
            uval[a] = u;
            if (u) atomicAdd(&hist[u >> 24], 1u);
        }
    }
    __syncthreads();

    if (tid == 0) {
        unsigned run = 0; int k1 = -1; unsigned above = 0;
        for (int k = 255; k >= 0; --k) {
            unsigned rn = run + hist[k];
            if (rn >= TOPK) { k1 = k; above = run; break; }
            run = rn;
        }
        scal[1] = k1; scal[2] = (int)above; scal[3] = 1;  // cutoff=1 if <100 valid
    }
    __syncthreads();
    const int k1 = scal[1];

    if (k1 >= 0) {
        // ---- level-2 (byte 2)
        hist[tid] = 0;
        __syncthreads();
        for (int a = tid; a < A_N; a += NTHR) {
            unsigned u = uval[a];
            if (u && (u >> 24) == (unsigned)k1) atomicAdd(&hist[(u >> 16) & 0xFFu], 1u);
        }
        __syncthreads();
        if (tid == 0) {
            unsigned run = (unsigned)scal[2]; int k2 = 0; unsigned above2 = run;
            for (int k = 255; k >= 0; --k) {
                unsigned rn = run + hist[k];
                if (rn >= TOPK) { k2 = k; above2 = run; break; }
                run = rn;
            }
            scal[4] = k2; scal[5] = (int)above2;
        }
        __syncthreads();
        const int k2 = scal[4];
        // ---- level-3 (byte 3)
        hist[tid] = 0;
        __syncthreads();
        const unsigned pfx16 = ((unsigned)k1 << 8) | (unsigned)k2;  // top 16 bits value
        for (int a = tid; a < A_N; a += NTHR) {
            unsigned u = uval[a];
            if (u && (u >> 16) == pfx16) atomicAdd(&hist[(u >> 8) & 0xFFu], 1u);
        }
        __syncthreads();
        if (tid == 0) {
            unsigned run = (unsigned)scal[5]; int k3 = 0;
            for (int k = 255; k >= 0; --k) {
                run += hist[k];
                if (run >= TOPK) { k3 = k; break; }
            }
            scal[3] = (int)((pfx16 << 16) | ((unsigned)k3 << 8));
        }
        __syncthreads();
    }
    const unsigned cutoff = (unsigned)scal[3];

    // ---- gather candidates >= cutoff (superset of top-100, ~101 expected)
    for (int a = tid; a < A_N; a += NTHR) {
        unsigned u = uval[a];
        if (u >= cutoff && u != 0u) {
            int pos = atomicAdd(&scal[0], 1);
            if (pos < CAND)
                cand[pos] = ((unsigned long long)u << 32) | (unsigned)(~(unsigned)a);
        }
    }
    __syncthreads();

    // ---- exact rank via all-pairs (LDS broadcast reads, order-independent)
    {
        unsigned long long mykey = cand[tid];
        int rank = 0;
        #pragma unroll 8
        for (int j = 0; j < CAND; ++j) rank += (cand[j] > mykey) ? 1 : 0;
        if (mykey != 0ull && rank < TOPK) ssel[rank] = mykey;
    }
    __syncthreads();

    // ---- decode top-100 boxes in f64 (reference op order)
    if (tid < TOPK) {
        unsigned long long key = ssel[tid];
        int valid = (key != 0ull);
        double b0 = 0, b1 = 0, b2 = 0, b3 = 0, area = 0, sc = 0;
        if (valid) {
            int a = (int)(~(unsigned)key);
            float x = unmapf((unsigned)(key >> 32));
            sc = 1.0 / (1.0 + exp(-(double)x));
            float4 r4 = *(const float4*)(boxreg + ((size_t)b * A_N + a) * 4);
            float4 p4 = *(const float4*)(priors + (size_t)a * 4);
            double ty = (double)r4.x / 10.0;
            double tx = (double)r4.y / 10.0;
            double th = (double)r4.z / 5.0;
            double tw = (double)r4.w / 5.0;
            double py = (double)p4.x, px = (double)p4.y;
            double ph = (double)p4.z, pw = (double)p4.w;
            double cy = ty * ph + py;
            double cx = tx * pw + px;
            double hh = exp(th) * ph;
            double ww = exp(tw) * pw;
            b0 = cy - hh / 2.0; b1 = cx - ww / 2.0;
            b2 = cy + hh / 2.0; b3 = cx + ww / 2.0;
            double e0 = b2 - b0; if (e0 < 0.0) e0 = 0.0;
            double e1 = b3 - b1; if (e1 < 0.0) e1 = 0.0;
            area = e0 * e1;
        }
        sb0[tid] = b0; sb1[tid] = b1; sb2[tid] = b2; sb3[tid] = b3;
        sarea[tid] = area; sscore[tid] = sc;
        svalid[tid] = valid;
    }
    __syncthreads();

    // ---- suppression bitmask: thread t handles row i = t>>1, word w = t&1
    if (tid < 2 * TOPK) {
        int i = tid >> 1, w = tid & 1;
        unsigned long long m = 0;
        if (svalid[i]) {
            double i0 = sb0[i], i1 = sb1[i], i2 = sb2[i], i3 = sb3[i], ia = sarea[i];
            int jbase = w * 64;
            int jend = min(jbase + 64, TOPK);
            int jstart = (jbase > i + 1) ? jbase : (i + 1);
            for (int j = jstart; j < jend; ++j) {
                double tl0 = fmax(i0, sb0[j]);
                double tl1 = fmax(i1, sb1[j]);
                double br0 = fmin(i2, sb2[j]);
                double br1 = fmin(i3, sb3[j]);
                double wh0 = br0 - tl0; if (wh0 < 0.0) wh0 = 0.0;
                double wh1 = br1 - tl1; if (wh1 < 0.0) wh1 = 0.0;
                double inter = wh0 * wh1;
                double iou = inter / (((ia + sarea[j]) - inter) + 1e-9);
                if (iou > 0.6) m |= 1ull << (j - jbase);
            }
        }
        supmask[i][w] = m;
    }
    __syncthreads();

    // ---- serial greedy scan over bitmasks (1 thread, ~100 iters, no barriers)
    if (tid == 0) {
        unsigned long long kp0 = ~0ull, kp1 = ~0ull;
        for (int i = 0; i < TOPK; ++i) {
            bool kb = (i < 64) ? ((kp0 >> i) & 1ull) : ((kp1 >> (i - 64)) & 1ull);
            if (kb && svalid[i]) { kp0 &= ~supmask[i][0]; kp1 &= ~supmask[i][1]; }
        }
        keepw[0] = kp0; keepw[1] = kp1;
    }
    __syncthreads();

    // ---- write 5 floats per slot
    if (tid < TOPK) {
        bool kb = (tid < 64) ? ((keepw[0] >> tid) & 1ull) : ((keepw[1] >> (tid - 64)) & 1ull);
        bool kp = kb && (svalid[tid] != 0);
        size_t base = ((size_t)task * TOPK + tid) * 5;
        out[base + 0] = kp ? (float)sb0[tid] : 0.0f;
        out[base + 1] = kp ? (float)sb1[tid] : 0.0f;
        out[base + 2] = kp ? (float)sb2[tid] : 0.0f;
        out[base + 3] = kp ? (float)sb3[tid] : 0.0f;
        out[base + 4] = kp ? (float)sscore[tid] : 0.0f;
    }
}

extern "C" void kernel_launch(void* const* d_in, const int* in_sizes, int n_in,
                              void* d_out, int out_size, void* d_ws, size_t ws_size,
                              hipStream_t stream) {
    const float* logits = (const float*)d_in[0];
    const float* boxreg = (const float*)d_in[1];
    const float* priors = (const float*)d_in[2];
    float* out = (float*)d_out;

    const size_t need = (size_t)B_N * NCLS * A_N * sizeof(unsigned);  // 89.4 MB
    if (ws_size >= need) {
        unsigned* keys = (unsigned*)d_ws;
        const int NT = (A_N + TA - 1) / TA;
        key_transpose_kernel<<<dim3(B_N * NT), dim3(NTHR), 0, stream>>>(logits, keys);
        ssd_nms_kernel<true><<<dim3(B_N * NCLS), dim3(NTHR), 0, stream>>>(
            logits, keys, boxreg, priors, out);
    } else {
        ssd_nms_kernel<false><<<dim3(B_N * NCLS), dim3(NTHR), 0, stream>>>(
            logits, nullptr, boxreg, priors, out);
    }
}

// Round 3
// 134.143 us; speedup vs baseline: 3.3157x; 2.4617x over previous
//
#include <hip/hip_runtime.h>
#include <math.h>

#define A_N   8732
#define C_N   81
#define B_N   32
#define NCLS  80
#define TOPK  100
#define NTHR  256
#define BINS  2048
#define SH    21          // 32 - 11 bits -> 2048 bins
#define CAND  320
#define TA    64

// ln(3/7) in f64: sigmoid_f64(x) > 0.3  <=>  x > THR_LOGIT
#define THR_LOGIT (-0.8472978603872034)

// Monotone map: float bits -> unsigned, order-preserving. 0 = invalid sentinel.
__device__ __forceinline__ unsigned mapf(float x) {
    unsigned b = __float_as_uint(x);
    return b ^ ((b & 0x80000000u) ? 0xFFFFFFFFu : 0x80000000u);
}
__device__ __forceinline__ float unmapf(unsigned u) {
    unsigned b = (u & 0x80000000u) ? (u ^ 0x80000000u) : ~u;
    return __uint_as_float(b);
}

// ---- Kernel T: coalesced logits read, keys transposed to (B, 80, A) ----
__global__ __launch_bounds__(NTHR) void key_transpose_kernel(
    const float* __restrict__ logits,    // (B, A, 81)
    unsigned* __restrict__ keys)         // (B, 80, A)
{
    __shared__ unsigned tile[NCLS][TA + 1];   // 80 x 65 words = 20.8 KB
    const int NT = (A_N + TA - 1) / TA;       // 137
    const int b  = blockIdx.x / NT;
    const int t0 = blockIdx.x % NT;
    const int a0 = t0 * TA;
    const int an = min(TA, A_N - a0);
    const int tid = threadIdx.x;

    const float* src = logits + ((size_t)b * A_N + a0) * C_N;

    if (an == TA) {
        const float4* src4 = (const float4*)src;
        const int total4 = TA * C_N / 4;      // 1296
        for (int i = tid; i < total4; i += NTHR) {
            float4 v = src4[i];
            int base = 4 * i;
            int r  = base / C_N;
            int ch = base - r * C_N;
            float xs[4] = { v.x, v.y, v.z, v.w };
            #pragma unroll
            for (int k = 0; k < 4; ++k) {
                if (ch > 0)
                    tile[ch - 1][r] = ((double)xs[k] > THR_LOGIT) ? mapf(xs[k]) : 0u;
                if (++ch == C_N) { ch = 0; ++r; }
            }
        }
        __syncthreads();
        const int R4 = TA / 4;                // 16 uint4 per class row
        for (int i = tid; i < NCLS * R4; i += NTHR) {
            int row = i >> 4, j = i & (R4 - 1);
            uint4 w;
            w.x = tile[row][4 * j + 0];
            w.y = tile[row][4 * j + 1];
            w.z = tile[row][4 * j + 2];
            w.w = tile[row][4 * j + 3];
            *(uint4*)(keys + ((size_t)b * NCLS + row) * A_N + a0 + 4 * j) = w;
        }
    } else {
        const int total = an * C_N;
        for (int i = tid; i < total; i += NTHR) {
            int r = i / C_N, ch = i - r * C_N;
            float x = src[i];
            if (ch > 0)
                tile[ch - 1][r] = ((double)x > THR_LOGIT) ? mapf(x) : 0u;
        }
        __syncthreads();
        for (int i = tid; i < NCLS * an; i += NTHR) {
            int row = i / an, col = i - row * an;
            keys[((size_t)b * NCLS + row) * A_N + a0 + col] = tile[row][col];
        }
    }
}

// ---- Kernel M: per-(b,c) top-100 select + decode + NMS ----
template<bool USE_WS>
__global__ __launch_bounds__(NTHR) void ssd_nms_kernel(
    const float* __restrict__ logits,
    const unsigned* __restrict__ keys,
    const float* __restrict__ boxreg,
    const float* __restrict__ priors,
    float* __restrict__ out)
{
    const int task = blockIdx.x;
    const int b = task / NCLS;
    const int c = task % NCLS;
    const int tid = threadIdx.x;

    __shared__ unsigned hist[BINS];               // 8 KB
    __shared__ unsigned bsum[NTHR];
    __shared__ unsigned long long cand[CAND];
    __shared__ unsigned long long ssel[TOPK];
    __shared__ double sb0[TOPK], sb1[TOPK], sb2[TOPK], sb3[TOPK];
    __shared__ double sarea[TOPK], sscore[TOPK];
    __shared__ int svalid[TOPK];
    __shared__ unsigned long long supmask[TOPK][2];
    __shared__ unsigned long long keepw[2];
    __shared__ int scal[2];

    const unsigned* krow = USE_WS ? (keys + ((size_t)b * NCLS + c) * A_N) : (const unsigned*)0;
    const float* lg = logits + ((size_t)b * A_N * C_N) + (c + 1);

    for (int k = tid; k < BINS; k += NTHR) hist[k] = 0;
    for (int i = tid; i < CAND; i += NTHR) cand[i] = 0ull;
    if (tid < TOPK) ssel[tid] = 0ull;
    if (tid == 0) { scal[0] = 0; scal[1] = 1; }   // scal[1]: cutoff, default "all valid"
    __syncthreads();

    // ---- Pass A: 2048-bin histogram of valid keys (low atomic contention)
    if (USE_WS) {
        const uint4* src = (const uint4*)krow;
        for (int i = tid; i < A_N / 4; i += NTHR) {
            uint4 v = src[i];
            if (v.x) atomicAdd(&hist[v.x >> SH], 1u);
            if (v.y) atomicAdd(&hist[v.y >> SH], 1u);
            if (v.z) atomicAdd(&hist[v.z >> SH], 1u);
            if (v.w) atomicAdd(&hist[v.w >> SH], 1u);
        }
    } else {
        for (int a = tid; a < A_N; a += NTHR) {
            float x = lg[(size_t)a * C_N];
            if ((double)x > THR_LOGIT) atomicAdd(&hist[mapf(x) >> SH], 1u);
        }
    }
    __syncthreads();

    // ---- parallel suffix scan to locate the 100th-largest key's bin
    {
        unsigned s = 0;
        #pragma unroll
        for (int k = 0; k < BINS / NTHR; ++k) s += hist[tid * (BINS / NTHR) + k];
        bsum[tid] = s;
    }
    __syncthreads();
    for (int off = 1; off < NTHR; off <<= 1) {
        unsigned v = (tid + off < NTHR) ? bsum[tid + off] : 0u;
        __syncthreads();
        bsum[tid] += v;
        __syncthreads();
    }
    {
        unsigned mine = bsum[tid];
        unsigned nxt = (tid < NTHR - 1) ? bsum[tid + 1] : 0u;
        if (mine >= TOPK && nxt < TOPK) {         // exactly one thread (if >=100 valid)
            unsigned running = nxt;
            #pragma unroll
            for (int k = BINS / NTHR - 1; k >= 0; --k) {
                running += hist[tid * (BINS / NTHR) + k];
                if (running >= TOPK) {
                    scal[1] = (int)(((unsigned)(tid * (BINS / NTHR) + k)) << SH);
                    break;
                }
            }
        }
    }
    __syncthreads();
    const unsigned cutoff = (unsigned)scal[1];

    // ---- Pass B: gather candidates >= cutoff (superset of top-100)
    if (USE_WS) {
        const uint4* src = (const uint4*)krow;
        for (int i = tid; i < A_N / 4; i += NTHR) {
            uint4 v = src[i];
            int a4 = 4 * i;
            if (v.x >= cutoff) {
                int p = atomicAdd(&scal[0], 1);
                if (p < CAND) cand[p] = ((unsigned long long)v.x << 32) | (unsigned)(~(unsigned)(a4 + 0));
            }
            if (v.y >= cutoff) {
                int p = atomicAdd(&scal[0], 1);
                if (p < CAND) cand[p] = ((unsigned long long)v.y << 32) | (unsigned)(~(unsigned)(a4 + 1));
            }
            if (v.z >= cutoff) {
                int p = atomicAdd(&scal[0], 1);
                if (p < CAND) cand[p] = ((unsigned long long)v.z << 32) | (unsigned)(~(unsigned)(a4 + 2));
            }
            if (v.w >= cutoff) {
                int p = atomicAdd(&scal[0], 1);
                if (p < CAND) cand[p] = ((unsigned long long)v.w << 32) | (unsigned)(~(unsigned)(a4 + 3));
            }
        }
    } else {
        for (int a = tid; a < A_N; a += NTHR) {
            float x = lg[(size_t)a * C_N];
            if ((double)x > THR_LOGIT) {
                unsigned u = mapf(x);
                if (u >= cutoff) {
                    int p = atomicAdd(&scal[0], 1);
                    if (p < CAND) cand[p] = ((unsigned long long)u << 32) | (unsigned)(~(unsigned)a);
                }
            }
        }
    }
    __syncthreads();

    // ---- exact rank via all-pairs over CAND (order-independent, broadcast reads)
    for (int i = tid; i < CAND; i += NTHR) {
        unsigned long long mykey = cand[i];
        int rank = 0;
        #pragma unroll 8
        for (int j = 0; j < CAND; ++j) rank += (cand[j] > mykey) ? 1 : 0;
        if (mykey != 0ull && rank < TOPK) ssel[rank] = mykey;
    }
    __syncthreads();

    // ---- decode top-100 boxes in f64 (reference op order)
    if (tid < TOPK) {
        unsigned long long key = ssel[tid];
        int valid = (key != 0ull);
        double b0 = 0, b1 = 0, b2 = 0, b3 = 0, area = 0, sc = 0;
        if (valid) {
            int a = (int)(~(unsigned)key);
            float x = unmapf((unsigned)(key >> 32));
            sc = 1.0 / (1.0 + exp(-(double)x));
            float4 r4 = *(const float4*)(boxreg + ((size_t)b * A_N + a) * 4);
            float4 p4 = *(const float4*)(priors + (size_t)a * 4);
            double ty = (double)r4.x / 10.0;
            double tx = (double)r4.y / 10.0;
            double th = (double)r4.z / 5.0;
            double tw = (double)r4.w / 5.0;
            double py = (double)p4.x, px = (double)p4.y;
            double ph = (double)p4.z, pw = (double)p4.w;
            double cy = ty * ph + py;
            double cx = tx * pw + px;
            double hh = exp(th) * ph;
            double ww = exp(tw) * pw;
            b0 = cy - hh / 2.0; b1 = cx - ww / 2.0;
            b2 = cy + hh / 2.0; b3 = cx + ww / 2.0;
            double e0 = b2 - b0; if (e0 < 0.0) e0 = 0.0;
            double e1 = b3 - b1; if (e1 < 0.0) e1 = 0.0;
            area = e0 * e1;
        }
        sb0[tid] = b0; sb1[tid] = b1; sb2[tid] = b2; sb3[tid] = b3;
        sarea[tid] = area; sscore[tid] = sc;
        svalid[tid] = valid;
    }
    __syncthreads();

    // ---- suppression bitmask: thread t -> row i = t>>1, mask word w = t&1
    if (tid < 2 * TOPK) {
        int i = tid >> 1, w = tid & 1;
        unsigned long long m = 0;
        if (svalid[i]) {
            double i0 = sb0[i], i1 = sb1[i], i2 = sb2[i], i3 = sb3[i], ia = sarea[i];
            int jbase = w * 64;
            int jend = min(jbase + 64, TOPK);
            int jstart = (jbase > i + 1) ? jbase : (i + 1);
            for (int j = jstart; j < jend; ++j) {
                double tl0 = fmax(i0, sb0[j]);
                double tl1 = fmax(i1, sb1[j]);
                double br0 = fmin(i2, sb2[j]);
                double br1 = fmin(i3, sb3[j]);
                double wh0 = br0 - tl0; if (wh0 < 0.0) wh0 = 0.0;
                double wh1 = br1 - tl1; if (wh1 < 0.0) wh1 = 0.0;
                double inter = wh0 * wh1;
                double iou = inter / (((ia + sarea[j]) - inter) + 1e-9);
                if (iou > 0.6) m |= 1ull << (j - jbase);
            }
        }
        supmask[i][w] = m;
    }
    __syncthreads();

    // ---- serial greedy scan over bitmasks
    if (tid == 0) {
        unsigned long long kp0 = ~0ull, kp1 = ~0ull;
        for (int i = 0; i < TOPK; ++i) {
            bool kb = (i < 64) ? ((kp0 >> i) & 1ull) : ((kp1 >> (i - 64)) & 1ull);
            if (kb && svalid[i]) { kp0 &= ~supmask[i][0]; kp1 &= ~supmask[i][1]; }
        }
        keepw[0] = kp0; keepw[1] = kp1;
    }
    __syncthreads();

    // ---- write 5 floats per slot
    if (tid < TOPK) {
        bool kb = (tid < 64) ? ((keepw[0] >> tid) & 1ull) : ((keepw[1] >> (tid - 64)) & 1ull);
        bool kp = kb && (svalid[tid] != 0);
        size_t base = ((size_t)task * TOPK + tid) * 5;
        out[base + 0] = kp ? (float)sb0[tid] : 0.0f;
        out[base + 1] = kp ? (float)sb1[tid] : 0.0f;
        out[base + 2] = kp ? (float)sb2[tid] : 0.0f;
        out[base + 3] = kp ? (float)sb3[tid] : 0.0f;
        out[base + 4] = kp ? (float)sscore[tid] : 0.0f;
    }
}

extern "C" void kernel_launch(void* const* d_in, const int* in_sizes, int n_in,
                              void* d_out, int out_size, void* d_ws, size_t ws_size,
                              hipStream_t stream) {
    const float* logits = (const float*)d_in[0];
    const float* boxreg = (const float*)d_in[1];
    const float* priors = (const float*)d_in[2];
    float* out = (float*)d_out;

    const size_t need = (size_t)B_N * NCLS * A_N * sizeof(unsigned);  // 89.4 MB
    if (ws_size >= need) {
        unsigned* keysw = (unsigned*)d_ws;
        const int NT = (A_N + TA - 1) / TA;
        key_transpose_kernel<<<dim3(B_N * NT), dim3(NTHR), 0, stream>>>(logits, keysw);
        ssd_nms_kernel<true><<<dim3(B_N * NCLS), dim3(NTHR), 0, stream>>>(
            logits, keysw, boxreg, priors, out);
    } else {
        ssd_nms_kernel<false><<<dim3(B_N * NCLS), dim3(NTHR), 0, stream>>>(
            logits, nullptr, boxreg, priors, out);
    }
}